// Round 4
// baseline (211.958 us; speedup 1.0000x reference)
//
#include <hip/hip_runtime.h>
#include <hip/hip_cooperative_groups.h>
#include <math.h>

namespace cg = cooperative_groups;

#define BB 2
#define MM 8192
#define NN (BB * MM)
#define NBATCH (NN / 16)      // 1024 batches of 16 sorted points
#define NCELL 4096            // 16^3 morton cells per cloud
#define LOSS_BLOCKS 1024

// ws layout (bytes):
#define PART_OFF   0          // 6 * LOSS_BLOCKS floats = 24576
#define RANK_OFF   24576      // NN ints = 65536
#define IDX_OFF    90112      // NN*16 ints = 1048576
#define PK_OFF     1138688    // NN float4 = 262144
#define SS_OFF     1400832    // NN floats = 65536
#define CELLID_OFF 1466368    // NN ints = 65536
#define CNT_OFF    1531904    // 2*NCELL ints = 32768
#define CUR_OFF    1564672    // 2*NCELL ints = 32768
#define BBLO_OFF   1597440    // NBATCH float4 = 16384
#define BBHI_OFF   1613824    // NBATCH float4 = 16384
#define DONE_OFF   1630208    // 1 unsigned (loss completion counter)

__device__ __forceinline__ unsigned mort3(unsigned x, unsigned y, unsigned z) {
    unsigned m = 0;
#pragma unroll
    for (int i = 0; i < 4; ++i) {
        m |= ((x >> i) & 1u) << (3 * i);
        m |= ((y >> i) & 1u) << (3 * i + 1);
        m |= ((z >> i) & 1u) << (3 * i + 2);
    }
    return m;
}

// R8: fused preprocessing — replaces memset+count+scan+scatter+bbox (5
// dispatches, ~8us launch overhead each) with ONE cooperative launch.
// 64 blocks x 1024 threads: trivially co-resident (no LDS pressure), so
// grid.sync() is safe. Phases identical to the old kernels.
__global__ __launch_bounds__(1024) void prep_kernel(
    const float* __restrict__ coords, const float* __restrict__ scores,
    int* __restrict__ cellid, int* __restrict__ cnt, int* __restrict__ cursor,
    float4* __restrict__ pk_s, float* __restrict__ s_s,
    float4* __restrict__ bb_lo, float4* __restrict__ bb_hi,
    unsigned* __restrict__ done) {
    cg::grid_group grid = cg::this_grid();
    __shared__ int wsum[16];
    const int tid = threadIdx.x, blk = blockIdx.x;

    // P0: zero cell counts (2*NCELL = 8192) + loss-done counter
    if (tid < 128) cnt[blk * 128 + tid] = 0;
    if (blk == 0 && tid == 0) *done = 0u;
    grid.sync();

    // P1: count (64 blocks x 256 active threads = NN)
    if (tid < 256) {
        const int i = blk * 256 + tid;
        float x = coords[3 * i], y = coords[3 * i + 1], z = coords[3 * i + 2];
        int cx = min(15, max(0, (int)floorf(x) + 8));
        int cy = min(15, max(0, (int)floorf(y) + 8));
        int cz = min(15, max(0, (int)floorf(z) + 8));
        int cid = (i >> 13) * NCELL + (int)mort3((unsigned)cx, (unsigned)cy, (unsigned)cz);
        cellid[i] = cid;
        atomicAdd(&cnt[cid], 1);
    }
    grid.sync();

    // P2: exclusive prefix over 8192 cell counts (block 0 only)
    if (blk == 0) {
        const int lane = tid & 63, wv = tid >> 6;
        int v[8]; int run = 0;
#pragma unroll
        for (int i = 0; i < 8; ++i) { int t = cnt[tid * 8 + i]; v[i] = run; run += t; }
        int inc = run;
#pragma unroll
        for (int off = 1; off < 64; off <<= 1) {
            int y = __shfl_up(inc, off);
            if (lane >= off) inc += y;
        }
        int laneExcl = inc - run;
        if (lane == 63) wsum[wv] = inc;
        __syncthreads();
        int wbase = 0;
#pragma unroll
        for (int w = 0; w < 16; ++w) wbase += (w < wv) ? wsum[w] : 0;
        const int base = wbase + laneExcl;
#pragma unroll
        for (int i = 0; i < 8; ++i) cursor[tid * 8 + i] = base + v[i];
    }
    grid.sync();

    // P3: scatter into morton-sorted order
    if (tid < 256) {
        const int i = blk * 256 + tid;
        int pos = atomicAdd(&cursor[cellid[i]], 1);
        float x = coords[3 * i], y = coords[3 * i + 1], z = coords[3 * i + 2];
        // MUST match dot ordering in knn so self-distance is exactly 0.
        float sq = fmaf(x, x, fmaf(y, y, z * z));
        pk_s[pos] = make_float4(x, y, z, sq);
        s_s[pos] = scores[i];
    }
    grid.sync();

    // P4: per-batch bboxes (64 blocks x 16 = NBATCH)
    if (tid < 16) {
        const int b = blk * 16 + tid;
        float4 c = pk_s[b * 16];
        float lx = c.x, ly = c.y, lz = c.z, hx = c.x, hy = c.y, hz = c.z;
#pragma unroll
        for (int i = 1; i < 16; ++i) {
            c = pk_s[b * 16 + i];
            lx = fminf(lx, c.x); ly = fminf(ly, c.y); lz = fminf(lz, c.z);
            hx = fmaxf(hx, c.x); hy = fmaxf(hy, c.y); hz = fmaxf(hz, c.z);
        }
        bb_lo[b] = make_float4(lx, ly, lz, 0.f);
        bb_hi[b] = make_float4(hx, hy, hz, 0.f);
    }
}

__device__ __forceinline__ void sort16(unsigned (&a)[16]) {
    // Batcher odd-even mergesort, ascending (verified, absmax 0)
#pragma unroll
    for (int p2 = 1; p2 < 16; p2 <<= 1) {
#pragma unroll
        for (int k2 = p2; k2 >= 1; k2 >>= 1) {
#pragma unroll
            for (int j2 = k2 % p2; j2 + k2 < 16; j2 += 2 * k2) {
#pragma unroll
                for (int i2 = 0; i2 < k2; ++i2) {
                    if (i2 + j2 + k2 < 16) {
                        if (((i2 + j2) / (2 * p2)) == ((i2 + j2 + k2) / (2 * p2))) {
                            unsigned x = a[i2 + j2], y = a[i2 + j2 + k2];
                            a[i2 + j2]      = min(x, y);
                            a[i2 + j2 + k2] = max(x, y);
                        }
                    }
                }
            }
        }
    }
}

__device__ __forceinline__ void truncmerge(unsigned (&slot)[16], const unsigned (&kb)[16]) {
    // lowest-16 of (sorted slot ∪ sorted kb), result sorted (verified)
    unsigned m[16];
#pragma unroll
    for (int k = 0; k < 16; ++k) m[k] = min(slot[k], kb[15 - k]);
#pragma unroll
    for (int st = 8; st >= 1; st >>= 1) {
#pragma unroll
        for (int i = 0; i < 16; ++i) {
            if ((i & st) == 0) {
                unsigned lo = min(m[i], m[i + st]);
                unsigned hi = max(m[i], m[i + st]);
                m[i] = lo; m[i + st] = hi;
            }
        }
    }
#pragma unroll
    for (int k = 0; k < 16; ++k) slot[k] = m[k];
}

// R8 fat kernel: blocks 0..255 = R0's proven knn core (63us) + ONE exact
// addition: per-lane shared bound lds_tmin maintained by LDS atomicMin
// (d2>=0 -> float bits are uint-monotone; bound is tie-safe masked+0x2000 of
// some wave's 16th-best, which upper-bounds the merged 16th-best -> pruning
// against it never drops a true top-16 member). Blocks 256..511 = rank,
// filling CUs concurrently (eliminates the separate rank dispatch).
__global__ __launch_bounds__(1024) void knnrank_kernel(const float4* __restrict__ pk_s,
                                                       const float* __restrict__ s_s,
                                                       const float4* __restrict__ bb_lo,
                                                       const float4* __restrict__ bb_hi,
                                                       int* __restrict__ out_idx,
                                                       int* __restrict__ out_rank) {
    __shared__ unsigned lds_k[16][16][64];
    __shared__ int lds_aux[16][64];
    __shared__ unsigned lds_tmin[64];
    const int tid = threadIdx.x, lane = tid & 63;
    const int wv = __builtin_amdgcn_readfirstlane(tid >> 6);

    if (blockIdx.x >= 256) {
        // ---- rank path: count of smaller scores within cloud ----
        const int qbase = (blockIdx.x - 256) << 6;
        const int cloudbase = (qbase >> 13) << 13;
        const float s = s_s[qbase + lane];
        const float* __restrict__ sc = s_s + cloudbase;
        int rk = 0;
        const int j0 = wv * 512;
        for (int jj = 0; jj < 512; jj += 16) {
#pragma unroll
            for (int i = 0; i < 16; ++i) {
                rk += (sc[j0 + jj + i] < s) ? 1 : 0;   // uniform -> scalar loads
            }
        }
        lds_aux[wv][lane] = rk;
        __syncthreads();
        if (wv == 0) {
            int rsum = 0;
#pragma unroll
            for (int w = 0; w < 16; ++w) rsum += lds_aux[w][lane];
            out_rank[qbase + lane] = rsum;
        }
        return;
    }

    // ---- knn path (R0 core) ----
    const int qbase = blockIdx.x * 64;
    const int cloudbase = (qbase >> 13) << 13;
    const float4 p = pk_s[qbase + lane];
    const int sb0 = (qbase - cloudbase) >> 4;      // first local batch (multiple of 4)
    const float4* __restrict__ pc = pk_s + cloudbase;
    const int bbase = cloudbase >> 4;

    if (tid < 64) lds_tmin[tid] = 0x7f7fffffu;     // FLT_MAX bits

    unsigned slot[16];
#pragma unroll
    for (int k = 0; k < 16; ++k) slot[k] = 0x7F000000u + (unsigned)k;  // > any real key
    float t_f = 3.0e38f;

    auto batch = [&](int bi) {
        unsigned kb[16];
#pragma unroll
        for (int i = 0; i < 16; ++i) {
            const int j = bi * 16 + i;             // uniform -> scalar loads
            const float4 c = pc[j];
            float dot = fmaf(p.x, c.x, fmaf(p.y, c.y, p.z * c.z));
            float d2  = fmaf(-2.0f, dot, p.w + c.w);   // exactly 0 for self
            kb[i] = (__float_as_uint(d2) & 0xFFFFE000u) | (unsigned)j;
        }
        sort16(kb);
        truncmerge(slot, kb);
        // conservative tie-safe upper bound of 16th-best d2
        const unsigned nt = (slot[15] & 0xFFFFE000u) + 0x2000u;
        const float ntf = __uint_as_float(nt);
        if (ntf < t_f) {
            t_f = ntf;
            atomicMin(&lds_tmin[lane], nt);
        }
    };

    // cooperative seed: wave owns local batch sb0+(wv-r) if wv in [r, r+4)
    const int r = sb0 & 15;
    const int ownb = (wv >= r && wv < r + 4) ? (sb0 + (wv - r)) : -1;  // uniform
    __syncthreads();                               // lds_tmin init visible
    if (ownb >= 0) batch(ownb);
    lds_aux[wv][lane] = (int)__float_as_uint(t_f);
    __syncthreads();
    float tb = __uint_as_float((unsigned)lds_aux[0][lane]);
#pragma unroll
    for (int w = 1; w < 16; ++w) tb = fminf(tb, __uint_as_float((unsigned)lds_aux[w][lane]));
    t_f = fminf(t_f, tb);

    // strided scan with bbox lower-bound pruning; prefetch next bbox pair.
    // Prune vs min(local bound, shared bound) -- shared tightens over time.
    float4 lo = bb_lo[bbase + wv];
    float4 hi = bb_hi[bbase + wv];
    for (int k = 0; k < 32; ++k) {
        const int bi = wv + (k << 4);
        float4 lo_n, hi_n;
        if (k + 1 < 32) {                          // uniform branch
            lo_n = bb_lo[bbase + bi + 16];
            hi_n = bb_hi[bbase + bi + 16];
        }
        if (bi != ownb) {                          // uniform skip (seeded already)
            const unsigned tmb = *((volatile unsigned*)&lds_tmin[lane]);
            const float tsh = fminf(t_f, __uint_as_float(tmb));
            float dx = fmaxf(fmaxf(lo.x - p.x, p.x - hi.x), 0.f);
            float dy = fmaxf(fmaxf(lo.y - p.y, p.y - hi.y), 0.f);
            float dz = fmaxf(fmaxf(lo.z - p.z, p.z - hi.z), 0.f);
            float lb = fmaf(dx, dx, fmaf(dy, dy, dz * dz));
            if (__any(fmaf(lb, 0.999f, -1e-5f) < tsh)) batch(bi);
        }
        lo = lo_n; hi = hi_n;
    }

#pragma unroll
    for (int k = 0; k < 16; ++k) lds_k[wv][k][lane] = slot[k];

    // tree merge 16 -> 1 sorted lists (verified)
    for (int half = 8; half >= 1; half >>= 1) {
        __syncthreads();
        if (wv < half) {
            unsigned a[16], m[16];
#pragma unroll
            for (int k = 0; k < 16; ++k) a[k] = lds_k[wv][k][lane];
#pragma unroll
            for (int k = 0; k < 16; ++k) m[k] = min(a[k], lds_k[wv + half][15 - k][lane]);
#pragma unroll
            for (int st = 8; st >= 1; st >>= 1) {
#pragma unroll
                for (int i = 0; i < 16; ++i) {
                    if ((i & st) == 0) {
                        unsigned lo2 = min(m[i], m[i + st]);
                        unsigned hi2 = max(m[i], m[i + st]);
                        m[i] = lo2; m[i + st] = hi2;
                    }
                }
            }
#pragma unroll
            for (int k = 0; k < 16; ++k) lds_k[wv][k][lane] = m[k];
        }
    }
    __syncthreads();

    if (wv == 0) {
#pragma unroll
        for (int k = 0; k < 16; ++k)
            out_idx[(qbase + lane) * 16 + k] = (int)(lds_k[0][k][lane] & 0x1FFFu) + cloudbase;
    }
}

// loss + fused finalization: last block to finish (device-scope counter)
// reduces the partials. The reduction replicates the old fin_kernel's exact
// tree (64-lane butterflies per group of 64, groups summed in order 0..15),
// so the result is bit-identical. Partials move with agent-scope
// release/acquire atomics for cross-XCD visibility.
__global__ __launch_bounds__(256) void lossfin_kernel(const float* __restrict__ s_s,
                                                      const float4* __restrict__ pk_s,
                                                      const int* __restrict__ knn,
                                                      const int* __restrict__ rnk,
                                                      float* __restrict__ partial,
                                                      unsigned* __restrict__ done,
                                                      float* __restrict__ out) {
    __shared__ float red[4][6];
    __shared__ float sgrp[16][6];
    __shared__ unsigned lastflag;
    const int t = blockIdx.x * 256 + threadIdx.x;
    const int q = t >> 4, k = t & 15;
    const int nb = knn[t];
    const float s  = s_s[q];
    const float sn = s_s[nb];
    const float diff = fabsf(s - sn);
    const float sim = 1.0f - diff;
    const float sg = 1.0f / (1.0f + expf(-2.0f * sim));

    float a_wd = 0.f, a_w = 0.f, a_pos = 0.f, a_neg = 0.f, snk = 0.f;
    if (k < 8) {
        float4 pq = pk_s[q];
        float4 pn = pk_s[nb];
        float dx = pq.x - pn.x, dy = pq.y - pn.y, dz = pq.z - pn.z;
        float d = sqrtf(dx * dx + dy * dy + dz * dz);
        float w = expf(-10.0f * d);
        a_wd = w * diff * diff;
        a_w  = w;
        a_pos = logf(sg + 1e-8f);
        snk = sn;
    } else {
        a_neg = logf(1.0f - sg + 1e-8f);
    }

    float nsum = snk;
#pragma unroll
    for (int off = 1; off < 16; off <<= 1) nsum += __shfl_xor(nsum, off);

    float a_sm = 0.f, a_di = 0.f;
    if (k == 0) {
        float t1 = s - nsum * 0.125f;
        a_sm = t1 * t1;
        float t2 = s - (float)rnk[q] * (1.0f / 8191.0f);
        a_di = t2 * t2;
    }

#pragma unroll
    for (int off = 1; off < 64; off <<= 1) {
        a_wd  += __shfl_xor(a_wd, off);
        a_w   += __shfl_xor(a_w, off);
        a_pos += __shfl_xor(a_pos, off);
        a_neg += __shfl_xor(a_neg, off);
        a_sm  += __shfl_xor(a_sm, off);
        a_di  += __shfl_xor(a_di, off);
    }
    const int wv = threadIdx.x >> 6;
    if ((threadIdx.x & 63) == 0) {
        red[wv][0] = a_wd; red[wv][1] = a_w; red[wv][2] = a_pos;
        red[wv][3] = a_neg; red[wv][4] = a_sm; red[wv][5] = a_di;
    }
    __syncthreads();
    if (threadIdx.x < 6) {
        float v = red[0][threadIdx.x] + red[1][threadIdx.x] +
                  red[2][threadIdx.x] + red[3][threadIdx.x];
        __hip_atomic_store(&partial[threadIdx.x * LOSS_BLOCKS + blockIdx.x], v,
                           __ATOMIC_RELEASE, __HIP_MEMORY_SCOPE_AGENT);
    }
    __syncthreads();
    if (threadIdx.x == 0)
        lastflag = __hip_atomic_fetch_add(done, 1u, __ATOMIC_ACQ_REL, __HIP_MEMORY_SCOPE_AGENT);
    __syncthreads();

    if (lastflag == (unsigned)(LOSS_BLOCKS - 1)) {
        const int tid = threadIdx.x, lane2 = tid & 63, w4 = tid >> 6;
#pragma unroll
        for (int rep = 0; rep < 4; ++rep) {
            const int w = w4 * 4 + rep;            // groups 0..15
            float a[6];
#pragma unroll
            for (int term = 0; term < 6; ++term)
                a[term] = __hip_atomic_load(&partial[term * LOSS_BLOCKS + w * 64 + lane2],
                                            __ATOMIC_ACQUIRE, __HIP_MEMORY_SCOPE_AGENT);
#pragma unroll
            for (int off = 1; off < 64; off <<= 1) {
#pragma unroll
                for (int term = 0; term < 6; ++term) a[term] += __shfl_xor(a[term], off);
            }
            if (lane2 == 0) {
#pragma unroll
                for (int term = 0; term < 6; ++term) sgrp[w][term] = a[term];
            }
        }
        __syncthreads();
        if (tid == 0) {
            float acc[6];
#pragma unroll
            for (int term = 0; term < 6; ++term) {
                float v = 0.f;
#pragma unroll
                for (int w = 0; w < 16; ++w) v += sgrp[w][term];
                acc[term] = v;
            }
            float l_loc = acc[0] / fmaxf(acc[1], 1e-8f);
            float l_pos = -acc[2] / (float)(NN * 8);
            float l_neg = -acc[3] / (float)(NN * 8);
            float l_sm  = acc[4] / (float)NN;
            float l_di  = acc[5] / (float)NN;
            out[0] = l_loc + 0.5f * (l_pos + l_neg) + 0.3f * l_di + 0.2f * l_sm;
        }
    }
}

extern "C" void kernel_launch(void* const* d_in, const int* in_sizes, int n_in,
                              void* d_out, int out_size, void* d_ws, size_t ws_size,
                              hipStream_t stream) {
    const float* scores = (const float*)d_in[0];
    const float* coords = (const float*)d_in[1];
    (void)in_sizes; (void)n_in; (void)out_size; (void)ws_size;

    char* ws = (char*)d_ws;
    float*  part  = (float*)(ws + PART_OFF);
    int*    rank  = (int*)(ws + RANK_OFF);
    int*    knn   = (int*)(ws + IDX_OFF);
    float4* pk_s  = (float4*)(ws + PK_OFF);
    float*  s_s   = (float*)(ws + SS_OFF);
    int*    cellid= (int*)(ws + CELLID_OFF);
    int*    cnt   = (int*)(ws + CNT_OFF);
    int*    cursor= (int*)(ws + CUR_OFF);
    float4* bb_lo = (float4*)(ws + BBLO_OFF);
    float4* bb_hi = (float4*)(ws + BBHI_OFF);
    unsigned* done= (unsigned*)(ws + DONE_OFF);
    float*  out   = (float*)d_out;

    void* prep_args[10] = { (void*)&coords, (void*)&scores, (void*)&cellid, (void*)&cnt,
                            (void*)&cursor, (void*)&pk_s, (void*)&s_s, (void*)&bb_lo,
                            (void*)&bb_hi, (void*)&done };
    hipLaunchCooperativeKernel(reinterpret_cast<void*>(prep_kernel),
                               dim3(64), dim3(1024), prep_args, 0, stream);
    knnrank_kernel<<<512, 1024, 0, stream>>>(pk_s, s_s, bb_lo, bb_hi, knn, rank);
    lossfin_kernel<<<LOSS_BLOCKS, 256, 0, stream>>>(s_s, pk_s, knn, rank, part, done, out);
}

// Round 5
// 168.082 us; speedup vs baseline: 1.2610x; 1.2610x over previous
//
#include <hip/hip_runtime.h>
#include <math.h>

#define BB 2
#define MM 8192
#define NN (BB * MM)
#define NBATCH (NN / 16)      // 1024 batches of 16 sorted points
#define NCELL 4096            // 16^3 morton cells per cloud
#define LOSS_BLOCKS 1024

// ws layout (bytes):
#define PART_OFF   0          // 6 * LOSS_BLOCKS floats = 24576
#define RANK_OFF   24576      // NN ints = 65536
#define IDX_OFF    90112      // NN*16 ints = 1048576
#define PK_OFF     1138688    // NN float4 = 262144
#define SS_OFF     1400832    // NN floats = 65536
#define DONE_OFF   1466368    // 1 unsigned (loss completion counter)
#define BBLO_OFF   1597440    // NBATCH float4 = 16384
#define BBHI_OFF   1613824    // NBATCH float4 = 16384

__device__ __forceinline__ unsigned mort3(unsigned x, unsigned y, unsigned z) {
    unsigned m = 0;
#pragma unroll
    for (int i = 0; i < 4; ++i) {
        m |= ((x >> i) & 1u) << (3 * i);
        m |= ((y >> i) & 1u) << (3 * i + 1);
        m |= ((z >> i) & 1u) << (3 * i + 2);
    }
    return m;
}

// R9 prep: ONE block per cloud (2 blocks x 1024 threads). The count->scan->
// scatter chain only needs ordering WITHIN a cloud (cells are per-cloud,
// scatter positions stay inside the cloud's [pbase, pbase+MM) range), so a
// per-cloud LDS histogram (16KB) + LDS block-scan + LDS-cursor scatter does
// the whole thing with __syncthreads() only. Replaces R8's cooperative
// launch whose grid.sync()s cost ~100us. bbox phase reads back the freshly
// scattered (L2-hot) points; __syncthreads orders global writes->reads
// within the block.
__global__ __launch_bounds__(1024) void prep_kernel(
    const float* __restrict__ coords, const float* __restrict__ scores,
    float4* __restrict__ pk_s, float* __restrict__ s_s,
    float4* __restrict__ bb_lo, float4* __restrict__ bb_hi,
    unsigned* __restrict__ done) {
    __shared__ int hist[NCELL];        // 4096 ints = 16 KB
    __shared__ int wsum[16];
    const int tid = threadIdx.x, blk = blockIdx.x;   // blk = cloud id
    const int pbase = blk * MM;
    for (int i = tid; i < NCELL; i += 1024) hist[i] = 0;
    if (blk == 0 && tid == 0) *done = 0u;
    __syncthreads();

    // P1: bin (8 points/thread), keep coords+cell in regs for the scatter
    int   cid[8];
    float px[8], py[8], pz[8];
#pragma unroll
    for (int it = 0; it < 8; ++it) {
        const int i = pbase + it * 1024 + tid;
        float x = coords[3 * i], y = coords[3 * i + 1], z = coords[3 * i + 2];
        int cx = min(15, max(0, (int)floorf(x) + 8));
        int cy = min(15, max(0, (int)floorf(y) + 8));
        int cz = min(15, max(0, (int)floorf(z) + 8));
        cid[it] = (int)mort3((unsigned)cx, (unsigned)cy, (unsigned)cz);
        px[it] = x; py[it] = y; pz[it] = z;
        atomicAdd(&hist[cid[it]], 1);
    }
    __syncthreads();

    // P2: exclusive scan over 4096 cell counts (4 cells/thread), in place
    int v[4]; int run = 0;
#pragma unroll
    for (int i = 0; i < 4; ++i) { int t = hist[tid * 4 + i]; v[i] = run; run += t; }
    const int lane = tid & 63, wv = tid >> 6;
    int inc = run;
#pragma unroll
    for (int off = 1; off < 64; off <<= 1) {
        int y = __shfl_up(inc, off);
        if (lane >= off) inc += y;
    }
    int laneExcl = inc - run;
    if (lane == 63) wsum[wv] = inc;
    __syncthreads();
    int wbase = 0;
#pragma unroll
    for (int w = 0; w < 16; ++w) wbase += (w < wv) ? wsum[w] : 0;
    const int base = wbase + laneExcl;
#pragma unroll
    for (int i = 0; i < 4; ++i) hist[tid * 4 + i] = base + v[i];   // own cells only
    __syncthreads();

    // P3: scatter into morton-sorted order (LDS cursor atomics)
#pragma unroll
    for (int it = 0; it < 8; ++it) {
        const int pos = pbase + atomicAdd(&hist[cid[it]], 1);
        const float x = px[it], y = py[it], z = pz[it];
        // MUST match dot ordering in knn so self-distance is exactly 0.
        const float sq = fmaf(x, x, fmaf(y, y, z * z));
        pk_s[pos] = make_float4(x, y, z, sq);
        s_s[pos] = scores[pbase + it * 1024 + tid];
    }
    __syncthreads();

    // P4: per-batch bboxes (512 batches/cloud, one per thread)
    if (tid < 512) {
        const int b = blk * 512 + tid;
        float4 c = pk_s[b * 16];
        float lx = c.x, ly = c.y, lz = c.z, hx = c.x, hy = c.y, hz = c.z;
#pragma unroll
        for (int i = 1; i < 16; ++i) {
            c = pk_s[b * 16 + i];
            lx = fminf(lx, c.x); ly = fminf(ly, c.y); lz = fminf(lz, c.z);
            hx = fmaxf(hx, c.x); hy = fmaxf(hy, c.y); hz = fmaxf(hz, c.z);
        }
        bb_lo[b] = make_float4(lx, ly, lz, 0.f);
        bb_hi[b] = make_float4(hx, hy, hz, 0.f);
    }
}

__device__ __forceinline__ void sort16(unsigned (&a)[16]) {
    // Batcher odd-even mergesort, ascending (verified, absmax 0)
#pragma unroll
    for (int p2 = 1; p2 < 16; p2 <<= 1) {
#pragma unroll
        for (int k2 = p2; k2 >= 1; k2 >>= 1) {
#pragma unroll
            for (int j2 = k2 % p2; j2 + k2 < 16; j2 += 2 * k2) {
#pragma unroll
                for (int i2 = 0; i2 < k2; ++i2) {
                    if (i2 + j2 + k2 < 16) {
                        if (((i2 + j2) / (2 * p2)) == ((i2 + j2 + k2) / (2 * p2))) {
                            unsigned x = a[i2 + j2], y = a[i2 + j2 + k2];
                            a[i2 + j2]      = min(x, y);
                            a[i2 + j2 + k2] = max(x, y);
                        }
                    }
                }
            }
        }
    }
}

__device__ __forceinline__ void truncmerge(unsigned (&slot)[16], const unsigned (&kb)[16]) {
    // lowest-16 of (sorted slot ∪ sorted kb), result sorted (verified)
    unsigned m[16];
#pragma unroll
    for (int k = 0; k < 16; ++k) m[k] = min(slot[k], kb[15 - k]);
#pragma unroll
    for (int st = 8; st >= 1; st >>= 1) {
#pragma unroll
        for (int i = 0; i < 16; ++i) {
            if ((i & st) == 0) {
                unsigned lo = min(m[i], m[i + st]);
                unsigned hi = max(m[i], m[i + st]);
                m[i] = lo; m[i + st] = hi;
            }
        }
    }
#pragma unroll
    for (int k = 0; k < 16; ++k) slot[k] = m[k];
}

// R8 fat kernel (proven 58us, absmax 0): blocks 0..255 = R0 knn core + exact
// per-lane shared bound via LDS atomicMin (d2>=0 -> float bits uint-monotone;
// tie-safe masked+0x2000 upper bound of the merged 16th-best). Blocks
// 256..511 = rank, concurrent in knn's shadow.
__global__ __launch_bounds__(1024) void knnrank_kernel(const float4* __restrict__ pk_s,
                                                       const float* __restrict__ s_s,
                                                       const float4* __restrict__ bb_lo,
                                                       const float4* __restrict__ bb_hi,
                                                       int* __restrict__ out_idx,
                                                       int* __restrict__ out_rank) {
    __shared__ unsigned lds_k[16][16][64];
    __shared__ int lds_aux[16][64];
    __shared__ unsigned lds_tmin[64];
    const int tid = threadIdx.x, lane = tid & 63;
    const int wv = __builtin_amdgcn_readfirstlane(tid >> 6);

    if (blockIdx.x >= 256) {
        // ---- rank path: count of smaller scores within cloud ----
        const int qbase = (blockIdx.x - 256) << 6;
        const int cloudbase = (qbase >> 13) << 13;
        const float s = s_s[qbase + lane];
        const float* __restrict__ sc = s_s + cloudbase;
        int rk = 0;
        const int j0 = wv * 512;
        for (int jj = 0; jj < 512; jj += 16) {
#pragma unroll
            for (int i = 0; i < 16; ++i) {
                rk += (sc[j0 + jj + i] < s) ? 1 : 0;   // uniform -> scalar loads
            }
        }
        lds_aux[wv][lane] = rk;
        __syncthreads();
        if (wv == 0) {
            int rsum = 0;
#pragma unroll
            for (int w = 0; w < 16; ++w) rsum += lds_aux[w][lane];
            out_rank[qbase + lane] = rsum;
        }
        return;
    }

    // ---- knn path (R0 core) ----
    const int qbase = blockIdx.x * 64;
    const int cloudbase = (qbase >> 13) << 13;
    const float4 p = pk_s[qbase + lane];
    const int sb0 = (qbase - cloudbase) >> 4;      // first local batch (multiple of 4)
    const float4* __restrict__ pc = pk_s + cloudbase;
    const int bbase = cloudbase >> 4;

    if (tid < 64) lds_tmin[tid] = 0x7f7fffffu;     // FLT_MAX bits

    unsigned slot[16];
#pragma unroll
    for (int k = 0; k < 16; ++k) slot[k] = 0x7F000000u + (unsigned)k;  // > any real key
    float t_f = 3.0e38f;

    auto batch = [&](int bi) {
        unsigned kb[16];
#pragma unroll
        for (int i = 0; i < 16; ++i) {
            const int j = bi * 16 + i;             // uniform -> scalar loads
            const float4 c = pc[j];
            float dot = fmaf(p.x, c.x, fmaf(p.y, c.y, p.z * c.z));
            float d2  = fmaf(-2.0f, dot, p.w + c.w);   // exactly 0 for self
            kb[i] = (__float_as_uint(d2) & 0xFFFFE000u) | (unsigned)j;
        }
        sort16(kb);
        truncmerge(slot, kb);
        // conservative tie-safe upper bound of 16th-best d2
        const unsigned nt = (slot[15] & 0xFFFFE000u) + 0x2000u;
        const float ntf = __uint_as_float(nt);
        if (ntf < t_f) {
            t_f = ntf;
            atomicMin(&lds_tmin[lane], nt);
        }
    };

    // cooperative seed: wave owns local batch sb0+(wv-r) if wv in [r, r+4)
    const int r = sb0 & 15;
    const int ownb = (wv >= r && wv < r + 4) ? (sb0 + (wv - r)) : -1;  // uniform
    __syncthreads();                               // lds_tmin init visible
    if (ownb >= 0) batch(ownb);
    lds_aux[wv][lane] = (int)__float_as_uint(t_f);
    __syncthreads();
    float tb = __uint_as_float((unsigned)lds_aux[0][lane]);
#pragma unroll
    for (int w = 1; w < 16; ++w) tb = fminf(tb, __uint_as_float((unsigned)lds_aux[w][lane]));
    t_f = fminf(t_f, tb);

    // strided scan with bbox lower-bound pruning; prefetch next bbox pair.
    // Prune vs min(local bound, shared bound) -- shared tightens over time.
    float4 lo = bb_lo[bbase + wv];
    float4 hi = bb_hi[bbase + wv];
    for (int k = 0; k < 32; ++k) {
        const int bi = wv + (k << 4);
        float4 lo_n, hi_n;
        if (k + 1 < 32) {                          // uniform branch
            lo_n = bb_lo[bbase + bi + 16];
            hi_n = bb_hi[bbase + bi + 16];
        }
        if (bi != ownb) {                          // uniform skip (seeded already)
            const unsigned tmb = *((volatile unsigned*)&lds_tmin[lane]);
            const float tsh = fminf(t_f, __uint_as_float(tmb));
            float dx = fmaxf(fmaxf(lo.x - p.x, p.x - hi.x), 0.f);
            float dy = fmaxf(fmaxf(lo.y - p.y, p.y - hi.y), 0.f);
            float dz = fmaxf(fmaxf(lo.z - p.z, p.z - hi.z), 0.f);
            float lb = fmaf(dx, dx, fmaf(dy, dy, dz * dz));
            if (__any(fmaf(lb, 0.999f, -1e-5f) < tsh)) batch(bi);
        }
        lo = lo_n; hi = hi_n;
    }

#pragma unroll
    for (int k = 0; k < 16; ++k) lds_k[wv][k][lane] = slot[k];

    // tree merge 16 -> 1 sorted lists (verified)
    for (int half = 8; half >= 1; half >>= 1) {
        __syncthreads();
        if (wv < half) {
            unsigned a[16], m[16];
#pragma unroll
            for (int k = 0; k < 16; ++k) a[k] = lds_k[wv][k][lane];
#pragma unroll
            for (int k = 0; k < 16; ++k) m[k] = min(a[k], lds_k[wv + half][15 - k][lane]);
#pragma unroll
            for (int st = 8; st >= 1; st >>= 1) {
#pragma unroll
                for (int i = 0; i < 16; ++i) {
                    if ((i & st) == 0) {
                        unsigned lo2 = min(m[i], m[i + st]);
                        unsigned hi2 = max(m[i], m[i + st]);
                        m[i] = lo2; m[i + st] = hi2;
                    }
                }
            }
#pragma unroll
            for (int k = 0; k < 16; ++k) lds_k[wv][k][lane] = m[k];
        }
    }
    __syncthreads();

    if (wv == 0) {
#pragma unroll
        for (int k = 0; k < 16; ++k)
            out_idx[(qbase + lane) * 16 + k] = (int)(lds_k[0][k][lane] & 0x1FFFu) + cloudbase;
    }
}

// loss + fused finalization (proven R8, bit-identical reduction tree):
// last block (agent-scope done counter) reduces the partials with the same
// 64-lane butterflies + ordered 16-group sum as the old fin_kernel.
__global__ __launch_bounds__(256) void lossfin_kernel(const float* __restrict__ s_s,
                                                      const float4* __restrict__ pk_s,
                                                      const int* __restrict__ knn,
                                                      const int* __restrict__ rnk,
                                                      float* __restrict__ partial,
                                                      unsigned* __restrict__ done,
                                                      float* __restrict__ out) {
    __shared__ float red[4][6];
    __shared__ float sgrp[16][6];
    __shared__ unsigned lastflag;
    const int t = blockIdx.x * 256 + threadIdx.x;
    const int q = t >> 4, k = t & 15;
    const int nb = knn[t];
    const float s  = s_s[q];
    const float sn = s_s[nb];
    const float diff = fabsf(s - sn);
    const float sim = 1.0f - diff;
    const float sg = 1.0f / (1.0f + expf(-2.0f * sim));

    float a_wd = 0.f, a_w = 0.f, a_pos = 0.f, a_neg = 0.f, snk = 0.f;
    if (k < 8) {
        float4 pq = pk_s[q];
        float4 pn = pk_s[nb];
        float dx = pq.x - pn.x, dy = pq.y - pn.y, dz = pq.z - pn.z;
        float d = sqrtf(dx * dx + dy * dy + dz * dz);
        float w = expf(-10.0f * d);
        a_wd = w * diff * diff;
        a_w  = w;
        a_pos = logf(sg + 1e-8f);
        snk = sn;
    } else {
        a_neg = logf(1.0f - sg + 1e-8f);
    }

    float nsum = snk;
#pragma unroll
    for (int off = 1; off < 16; off <<= 1) nsum += __shfl_xor(nsum, off);

    float a_sm = 0.f, a_di = 0.f;
    if (k == 0) {
        float t1 = s - nsum * 0.125f;
        a_sm = t1 * t1;
        float t2 = s - (float)rnk[q] * (1.0f / 8191.0f);
        a_di = t2 * t2;
    }

#pragma unroll
    for (int off = 1; off < 64; off <<= 1) {
        a_wd  += __shfl_xor(a_wd, off);
        a_w   += __shfl_xor(a_w, off);
        a_pos += __shfl_xor(a_pos, off);
        a_neg += __shfl_xor(a_neg, off);
        a_sm  += __shfl_xor(a_sm, off);
        a_di  += __shfl_xor(a_di, off);
    }
    const int wv = threadIdx.x >> 6;
    if ((threadIdx.x & 63) == 0) {
        red[wv][0] = a_wd; red[wv][1] = a_w; red[wv][2] = a_pos;
        red[wv][3] = a_neg; red[wv][4] = a_sm; red[wv][5] = a_di;
    }
    __syncthreads();
    if (threadIdx.x < 6) {
        float v = red[0][threadIdx.x] + red[1][threadIdx.x] +
                  red[2][threadIdx.x] + red[3][threadIdx.x];
        __hip_atomic_store(&partial[threadIdx.x * LOSS_BLOCKS + blockIdx.x], v,
                           __ATOMIC_RELEASE, __HIP_MEMORY_SCOPE_AGENT);
    }
    __syncthreads();
    if (threadIdx.x == 0)
        lastflag = __hip_atomic_fetch_add(done, 1u, __ATOMIC_ACQ_REL, __HIP_MEMORY_SCOPE_AGENT);
    __syncthreads();

    if (lastflag == (unsigned)(LOSS_BLOCKS - 1)) {
        const int tid = threadIdx.x, lane2 = tid & 63, w4 = tid >> 6;
#pragma unroll
        for (int rep = 0; rep < 4; ++rep) {
            const int w = w4 * 4 + rep;            // groups 0..15
            float a[6];
#pragma unroll
            for (int term = 0; term < 6; ++term)
                a[term] = __hip_atomic_load(&partial[term * LOSS_BLOCKS + w * 64 + lane2],
                                            __ATOMIC_ACQUIRE, __HIP_MEMORY_SCOPE_AGENT);
#pragma unroll
            for (int off = 1; off < 64; off <<= 1) {
#pragma unroll
                for (int term = 0; term < 6; ++term) a[term] += __shfl_xor(a[term], off);
            }
            if (lane2 == 0) {
#pragma unroll
                for (int term = 0; term < 6; ++term) sgrp[w][term] = a[term];
            }
        }
        __syncthreads();
        if (tid == 0) {
            float acc[6];
#pragma unroll
            for (int term = 0; term < 6; ++term) {
                float v = 0.f;
#pragma unroll
                for (int w = 0; w < 16; ++w) v += sgrp[w][term];
                acc[term] = v;
            }
            float l_loc = acc[0] / fmaxf(acc[1], 1e-8f);
            float l_pos = -acc[2] / (float)(NN * 8);
            float l_neg = -acc[3] / (float)(NN * 8);
            float l_sm  = acc[4] / (float)NN;
            float l_di  = acc[5] / (float)NN;
            out[0] = l_loc + 0.5f * (l_pos + l_neg) + 0.3f * l_di + 0.2f * l_sm;
        }
    }
}

extern "C" void kernel_launch(void* const* d_in, const int* in_sizes, int n_in,
                              void* d_out, int out_size, void* d_ws, size_t ws_size,
                              hipStream_t stream) {
    const float* scores = (const float*)d_in[0];
    const float* coords = (const float*)d_in[1];
    (void)in_sizes; (void)n_in; (void)out_size; (void)ws_size;

    char* ws = (char*)d_ws;
    float*  part  = (float*)(ws + PART_OFF);
    int*    rank  = (int*)(ws + RANK_OFF);
    int*    knn   = (int*)(ws + IDX_OFF);
    float4* pk_s  = (float4*)(ws + PK_OFF);
    float*  s_s   = (float*)(ws + SS_OFF);
    float4* bb_lo = (float4*)(ws + BBLO_OFF);
    float4* bb_hi = (float4*)(ws + BBHI_OFF);
    unsigned* done= (unsigned*)(ws + DONE_OFF);
    float*  out   = (float*)d_out;

    prep_kernel<<<2, 1024, 0, stream>>>(coords, scores, pk_s, s_s, bb_lo, bb_hi, done);
    knnrank_kernel<<<512, 1024, 0, stream>>>(pk_s, s_s, bb_lo, bb_hi, knn, rank);
    lossfin_kernel<<<LOSS_BLOCKS, 256, 0, stream>>>(s_s, pk_s, knn, rank, part, done, out);
}

// Round 7
// 159.797 us; speedup vs baseline: 1.3264x; 1.0518x over previous
//
#include <hip/hip_runtime.h>
#include <math.h>

#define BB 2
#define MM 8192
#define NN (BB * MM)
#define NBATCH (NN / 16)      // 1024 batches of 16 sorted points
#define NCELL 4096            // 16^3 morton cells per cloud
#define LOSS_BLOCKS 1024

// ws layout (bytes):
#define PART_OFF   0          // 6 * LOSS_BLOCKS floats = 24576
#define RANK_OFF   24576      // NN ints = 65536
#define IDX_OFF    90112      // NN*16 ints = 1048576
#define PK_OFF     1138688    // NN float4 = 262144
#define SS_OFF     1400832    // NN floats = 65536
#define CELLID_OFF 1466368    // NN ints = 65536
#define CNT_OFF    1531904    // (unused this round)
#define CUR_OFF    1564672    // 2*NCELL ints = 32768
#define BBLO_OFF   1597440    // NBATCH float4 = 16384
#define BBHI_OFF   1613824    // NBATCH float4 = 16384
#define DONE_OFF   1630208    // 1 unsigned (loss completion counter)

__device__ __forceinline__ unsigned mort3(unsigned x, unsigned y, unsigned z) {
    unsigned m = 0;
#pragma unroll
    for (int i = 0; i < 4; ++i) {
        m |= ((x >> i) & 1u) << (3 * i);
        m |= ((y >> i) & 1u) << (3 * i + 1);
        m |= ((z >> i) & 1u) << (3 * i + 2);
    }
    return m;
}

// R10 prepA: one block per cloud. ONLY the cheap per-cloud serial parts:
// LDS histogram (16KB, replaces global memset+count) + LDS block-scan ->
// global cursor + cellid. The expensive scattered stores go back to a
// massively-parallel scatter kernel (R5's 2-CU prep serialized them).
__global__ __launch_bounds__(1024) void prepA_kernel(
    const float* __restrict__ coords, int* __restrict__ cellid,
    int* __restrict__ cursor, unsigned* __restrict__ done) {
    __shared__ int hist[NCELL];        // 4096 ints = 16 KB
    __shared__ int wsum[16];
    const int tid = threadIdx.x, blk = blockIdx.x;   // blk = cloud id
    const int pbase = blk * MM;
    for (int i = tid; i < NCELL; i += 1024) hist[i] = 0;
    if (blk == 0 && tid == 0) *done = 0u;
    __syncthreads();

    // bin 8 points/thread (coalesced across lanes)
#pragma unroll
    for (int it = 0; it < 8; ++it) {
        const int i = pbase + it * 1024 + tid;
        float x = coords[3 * i], y = coords[3 * i + 1], z = coords[3 * i + 2];
        int cx = min(15, max(0, (int)floorf(x) + 8));
        int cy = min(15, max(0, (int)floorf(y) + 8));
        int cz = min(15, max(0, (int)floorf(z) + 8));
        const int c = (int)mort3((unsigned)cx, (unsigned)cy, (unsigned)cz);
        cellid[i] = blk * NCELL + c;
        atomicAdd(&hist[c], 1);
    }
    __syncthreads();

    // exclusive scan over 4096 cell counts (4 cells/thread) -> global cursor
    int v[4]; int run = 0;
#pragma unroll
    for (int i = 0; i < 4; ++i) { int t = hist[tid * 4 + i]; v[i] = run; run += t; }
    const int lane = tid & 63, wv = tid >> 6;
    int inc = run;
#pragma unroll
    for (int off = 1; off < 64; off <<= 1) {
        int y = __shfl_up(inc, off);
        if (lane >= off) inc += y;
    }
    int laneExcl = inc - run;
    if (lane == 63) wsum[wv] = inc;
    __syncthreads();
    int wbase = 0;
#pragma unroll
    for (int w = 0; w < 16; ++w) wbase += (w < wv) ? wsum[w] : 0;
    const int base = wbase + laneExcl;   // cloud-local exclusive prefix
#pragma unroll
    for (int i = 0; i < 4; ++i)
        cursor[blk * NCELL + tid * 4 + i] = pbase + base + v[i];
}

// R0's proven scatter: massively parallel, global cursor atomics
__global__ void scatter_kernel(const float* __restrict__ coords, const float* __restrict__ scores,
                               const int* __restrict__ cellid, int* __restrict__ cursor,
                               float4* __restrict__ pk_s, float* __restrict__ s_s) {
    int i = blockIdx.x * 256 + threadIdx.x;
    if (i < NN) {
        int pos = atomicAdd(&cursor[cellid[i]], 1);
        float x = coords[3 * i], y = coords[3 * i + 1], z = coords[3 * i + 2];
        // MUST match dot ordering in knn_kernel so self-distance is exactly 0.
        float sq = fmaf(x, x, fmaf(y, y, z * z));
        pk_s[pos] = make_float4(x, y, z, sq);
        s_s[pos] = scores[i];
    }
}

__global__ void bbox_kernel(const float4* __restrict__ pk_s, float4* __restrict__ bb_lo,
                            float4* __restrict__ bb_hi) {
    int b = blockIdx.x * 256 + threadIdx.x;
    if (b < NBATCH) {
        float4 c = pk_s[b * 16];
        float lx = c.x, ly = c.y, lz = c.z, hx = c.x, hy = c.y, hz = c.z;
#pragma unroll
        for (int i = 1; i < 16; ++i) {
            c = pk_s[b * 16 + i];
            lx = fminf(lx, c.x); ly = fminf(ly, c.y); lz = fminf(lz, c.z);
            hx = fmaxf(hx, c.x); hy = fmaxf(hy, c.y); hz = fmaxf(hz, c.z);
        }
        bb_lo[b] = make_float4(lx, ly, lz, 0.f);
        bb_hi[b] = make_float4(hx, hy, hz, 0.f);
    }
}

__device__ __forceinline__ void sort16(unsigned (&a)[16]) {
    // Batcher odd-even mergesort, ascending (verified, absmax 0)
#pragma unroll
    for (int p2 = 1; p2 < 16; p2 <<= 1) {
#pragma unroll
        for (int k2 = p2; k2 >= 1; k2 >>= 1) {
#pragma unroll
            for (int j2 = k2 % p2; j2 + k2 < 16; j2 += 2 * k2) {
#pragma unroll
                for (int i2 = 0; i2 < k2; ++i2) {
                    if (i2 + j2 + k2 < 16) {
                        if (((i2 + j2) / (2 * p2)) == ((i2 + j2 + k2) / (2 * p2))) {
                            unsigned x = a[i2 + j2], y = a[i2 + j2 + k2];
                            a[i2 + j2]      = min(x, y);
                            a[i2 + j2 + k2] = max(x, y);
                        }
                    }
                }
            }
        }
    }
}

__device__ __forceinline__ void truncmerge(unsigned (&slot)[16], const unsigned (&kb)[16]) {
    // lowest-16 of (sorted slot ∪ sorted kb), result sorted (verified)
    unsigned m[16];
#pragma unroll
    for (int k = 0; k < 16; ++k) m[k] = min(slot[k], kb[15 - k]);
#pragma unroll
    for (int st = 8; st >= 1; st >>= 1) {
#pragma unroll
        for (int i = 0; i < 16; ++i) {
            if ((i & st) == 0) {
                unsigned lo = min(m[i], m[i + st]);
                unsigned hi = max(m[i], m[i + st]);
                m[i] = lo; m[i + st] = hi;
            }
        }
    }
#pragma unroll
    for (int k = 0; k < 16; ++k) slot[k] = m[k];
}

// Proven 56us fat kernel (R4/R5, absmax 0): blocks 0..255 = R0 knn core +
// exact per-lane shared bound via LDS atomicMin (d2>=0 -> float bits
// uint-monotone; tie-safe masked+0x2000 upper bound of the merged 16th-best).
// Blocks 256..511 = rank, concurrent in knn's shadow.
__global__ __launch_bounds__(1024) void knnrank_kernel(const float4* __restrict__ pk_s,
                                                       const float* __restrict__ s_s,
                                                       const float4* __restrict__ bb_lo,
                                                       const float4* __restrict__ bb_hi,
                                                       int* __restrict__ out_idx,
                                                       int* __restrict__ out_rank) {
    __shared__ unsigned lds_k[16][16][64];
    __shared__ int lds_aux[16][64];
    __shared__ unsigned lds_tmin[64];
    const int tid = threadIdx.x, lane = tid & 63;
    const int wv = __builtin_amdgcn_readfirstlane(tid >> 6);

    if (blockIdx.x >= 256) {
        // ---- rank path: count of smaller scores within cloud ----
        const int qbase = (blockIdx.x - 256) << 6;
        const int cloudbase = (qbase >> 13) << 13;
        const float s = s_s[qbase + lane];
        const float* __restrict__ sc = s_s + cloudbase;
        int rk = 0;
        const int j0 = wv * 512;
        for (int jj = 0; jj < 512; jj += 16) {
#pragma unroll
            for (int i = 0; i < 16; ++i) {
                rk += (sc[j0 + jj + i] < s) ? 1 : 0;   // uniform -> scalar loads
            }
        }
        lds_aux[wv][lane] = rk;
        __syncthreads();
        if (wv == 0) {
            int rsum = 0;
#pragma unroll
            for (int w = 0; w < 16; ++w) rsum += lds_aux[w][lane];
            out_rank[qbase + lane] = rsum;
        }
        return;
    }

    // ---- knn path (R0 core) ----
    const int qbase = blockIdx.x * 64;
    const int cloudbase = (qbase >> 13) << 13;
    const float4 p = pk_s[qbase + lane];
    const int sb0 = (qbase - cloudbase) >> 4;      // first local batch (multiple of 4)
    const float4* __restrict__ pc = pk_s + cloudbase;
    const int bbase = cloudbase >> 4;

    if (tid < 64) lds_tmin[tid] = 0x7f7fffffu;     // FLT_MAX bits

    unsigned slot[16];
#pragma unroll
    for (int k = 0; k < 16; ++k) slot[k] = 0x7F000000u + (unsigned)k;  // > any real key
    float t_f = 3.0e38f;

    auto batch = [&](int bi) {
        unsigned kb[16];
#pragma unroll
        for (int i = 0; i < 16; ++i) {
            const int j = bi * 16 + i;             // uniform -> scalar loads
            const float4 c = pc[j];
            float dot = fmaf(p.x, c.x, fmaf(p.y, c.y, p.z * c.z));
            float d2  = fmaf(-2.0f, dot, p.w + c.w);   // exactly 0 for self
            kb[i] = (__float_as_uint(d2) & 0xFFFFE000u) | (unsigned)j;
        }
        sort16(kb);
        truncmerge(slot, kb);
        // conservative tie-safe upper bound of 16th-best d2
        const unsigned nt = (slot[15] & 0xFFFFE000u) + 0x2000u;
        const float ntf = __uint_as_float(nt);
        if (ntf < t_f) {
            t_f = ntf;
            atomicMin(&lds_tmin[lane], nt);
        }
    };

    // cooperative seed: wave owns local batch sb0+(wv-r) if wv in [r, r+4)
    const int r = sb0 & 15;
    const int ownb = (wv >= r && wv < r + 4) ? (sb0 + (wv - r)) : -1;  // uniform
    __syncthreads();                               // lds_tmin init visible
    if (ownb >= 0) batch(ownb);
    lds_aux[wv][lane] = (int)__float_as_uint(t_f);
    __syncthreads();
    float tb = __uint_as_float((unsigned)lds_aux[0][lane]);
#pragma unroll
    for (int w = 1; w < 16; ++w) tb = fminf(tb, __uint_as_float((unsigned)lds_aux[w][lane]));
    t_f = fminf(t_f, tb);

    // strided scan with bbox lower-bound pruning; prefetch next bbox pair.
    // Prune vs min(local bound, shared bound) -- shared tightens over time.
    float4 lo = bb_lo[bbase + wv];
    float4 hi = bb_hi[bbase + wv];
    for (int k = 0; k < 32; ++k) {
        const int bi = wv + (k << 4);
        float4 lo_n, hi_n;
        if (k + 1 < 32) {                          // uniform branch
            lo_n = bb_lo[bbase + bi + 16];
            hi_n = bb_hi[bbase + bi + 16];
        }
        if (bi != ownb) {                          // uniform skip (seeded already)
            const unsigned tmb = *((volatile unsigned*)&lds_tmin[lane]);
            const float tsh = fminf(t_f, __uint_as_float(tmb));
            float dx = fmaxf(fmaxf(lo.x - p.x, p.x - hi.x), 0.f);
            float dy = fmaxf(fmaxf(lo.y - p.y, p.y - hi.y), 0.f);
            float dz = fmaxf(fmaxf(lo.z - p.z, p.z - hi.z), 0.f);
            float lb = fmaf(dx, dx, fmaf(dy, dy, dz * dz));
            if (__any(fmaf(lb, 0.999f, -1e-5f) < tsh)) batch(bi);
        }
        lo = lo_n; hi = hi_n;
    }

#pragma unroll
    for (int k = 0; k < 16; ++k) lds_k[wv][k][lane] = slot[k];

    // tree merge 16 -> 1 sorted lists (verified)
    for (int half = 8; half >= 1; half >>= 1) {
        __syncthreads();
        if (wv < half) {
            unsigned a[16], m[16];
#pragma unroll
            for (int k = 0; k < 16; ++k) a[k] = lds_k[wv][k][lane];
#pragma unroll
            for (int k = 0; k < 16; ++k) m[k] = min(a[k], lds_k[wv + half][15 - k][lane]);
#pragma unroll
            for (int st = 8; st >= 1; st >>= 1) {
#pragma unroll
                for (int i = 0; i < 16; ++i) {
                    if ((i & st) == 0) {
                        unsigned lo2 = min(m[i], m[i + st]);
                        unsigned hi2 = max(m[i], m[i + st]);
                        m[i] = lo2; m[i + st] = hi2;
                    }
                }
            }
#pragma unroll
            for (int k = 0; k < 16; ++k) lds_k[wv][k][lane] = m[k];
        }
    }
    __syncthreads();

    if (wv == 0) {
#pragma unroll
        for (int k = 0; k < 16; ++k)
            out_idx[(qbase + lane) * 16 + k] = (int)(lds_k[0][k][lane] & 0x1FFFu) + cloudbase;
    }
}

// loss + fused finalization (proven R4/R5, bit-identical reduction tree):
// last block (agent-scope done counter) reduces the partials with the same
// 64-lane butterflies + ordered 16-group sum as the old fin_kernel.
__global__ __launch_bounds__(256) void lossfin_kernel(const float* __restrict__ s_s,
                                                      const float4* __restrict__ pk_s,
                                                      const int* __restrict__ knn,
                                                      const int* __restrict__ rnk,
                                                      float* __restrict__ partial,
                                                      unsigned* __restrict__ done,
                                                      float* __restrict__ out) {
    __shared__ float red[4][6];
    __shared__ float sgrp[16][6];
    __shared__ unsigned lastflag;
    const int t = blockIdx.x * 256 + threadIdx.x;
    const int q = t >> 4, k = t & 15;
    const int nb = knn[t];
    const float s  = s_s[q];
    const float sn = s_s[nb];
    const float diff = fabsf(s - sn);
    const float sim = 1.0f - diff;
    const float sg = 1.0f / (1.0f + expf(-2.0f * sim));

    float a_wd = 0.f, a_w = 0.f, a_pos = 0.f, a_neg = 0.f, snk = 0.f;
    if (k < 8) {
        float4 pq = pk_s[q];
        float4 pn = pk_s[nb];
        float dx = pq.x - pn.x, dy = pq.y - pn.y, dz = pq.z - pn.z;
        float d = sqrtf(dx * dx + dy * dy + dz * dz);
        float w = expf(-10.0f * d);
        a_wd = w * diff * diff;
        a_w  = w;
        a_pos = logf(sg + 1e-8f);
        snk = sn;
    } else {
        a_neg = logf(1.0f - sg + 1e-8f);
    }

    float nsum = snk;
#pragma unroll
    for (int off = 1; off < 16; off <<= 1) nsum += __shfl_xor(nsum, off);

    float a_sm = 0.f, a_di = 0.f;
    if (k == 0) {
        float t1 = s - nsum * 0.125f;
        a_sm = t1 * t1;
        float t2 = s - (float)rnk[q] * (1.0f / 8191.0f);
        a_di = t2 * t2;
    }

#pragma unroll
    for (int off = 1; off < 64; off <<= 1) {
        a_wd  += __shfl_xor(a_wd, off);
        a_w   += __shfl_xor(a_w, off);
        a_pos += __shfl_xor(a_pos, off);
        a_neg += __shfl_xor(a_neg, off);
        a_sm  += __shfl_xor(a_sm, off);
        a_di  += __shfl_xor(a_di, off);
    }
    const int wv = threadIdx.x >> 6;
    if ((threadIdx.x & 63) == 0) {
        red[wv][0] = a_wd; red[wv][1] = a_w; red[wv][2] = a_pos;
        red[wv][3] = a_neg; red[wv][4] = a_sm; red[wv][5] = a_di;
    }
    __syncthreads();
    if (threadIdx.x < 6) {
        float v = red[0][threadIdx.x] + red[1][threadIdx.x] +
                  red[2][threadIdx.x] + red[3][threadIdx.x];
        __hip_atomic_store(&partial[threadIdx.x * LOSS_BLOCKS + blockIdx.x], v,
                           __ATOMIC_RELEASE, __HIP_MEMORY_SCOPE_AGENT);
    }
    __syncthreads();
    if (threadIdx.x == 0)
        lastflag = __hip_atomic_fetch_add(done, 1u, __ATOMIC_ACQ_REL, __HIP_MEMORY_SCOPE_AGENT);
    __syncthreads();

    if (lastflag == (unsigned)(LOSS_BLOCKS - 1)) {
        const int tid = threadIdx.x, lane2 = tid & 63, w4 = tid >> 6;
#pragma unroll
        for (int rep = 0; rep < 4; ++rep) {
            const int w = w4 * 4 + rep;            // groups 0..15
            float a[6];
#pragma unroll
            for (int term = 0; term < 6; ++term)
                a[term] = __hip_atomic_load(&partial[term * LOSS_BLOCKS + w * 64 + lane2],
                                            __ATOMIC_ACQUIRE, __HIP_MEMORY_SCOPE_AGENT);
#pragma unroll
            for (int off = 1; off < 64; off <<= 1) {
#pragma unroll
                for (int term = 0; term < 6; ++term) a[term] += __shfl_xor(a[term], off);
            }
            if (lane2 == 0) {
#pragma unroll
                for (int term = 0; term < 6; ++term) sgrp[w][term] = a[term];
            }
        }
        __syncthreads();
        if (tid == 0) {
            float acc[6];
#pragma unroll
            for (int term = 0; term < 6; ++term) {
                float v = 0.f;
#pragma unroll
                for (int w = 0; w < 16; ++w) v += sgrp[w][term];
                acc[term] = v;
            }
            float l_loc = acc[0] / fmaxf(acc[1], 1e-8f);
            float l_pos = -acc[2] / (float)(NN * 8);
            float l_neg = -acc[3] / (float)(NN * 8);
            float l_sm  = acc[4] / (float)NN;
            float l_di  = acc[5] / (float)NN;
            out[0] = l_loc + 0.5f * (l_pos + l_neg) + 0.3f * l_di + 0.2f * l_sm;
        }
    }
}

extern "C" void kernel_launch(void* const* d_in, const int* in_sizes, int n_in,
                              void* d_out, int out_size, void* d_ws, size_t ws_size,
                              hipStream_t stream) {
    const float* scores = (const float*)d_in[0];
    const float* coords = (const float*)d_in[1];
    (void)in_sizes; (void)n_in; (void)out_size; (void)ws_size;

    char* ws = (char*)d_ws;
    float*  part  = (float*)(ws + PART_OFF);
    int*    rank  = (int*)(ws + RANK_OFF);
    int*    knn   = (int*)(ws + IDX_OFF);
    float4* pk_s  = (float4*)(ws + PK_OFF);
    float*  s_s   = (float*)(ws + SS_OFF);
    int*    cellid= (int*)(ws + CELLID_OFF);
    int*    cursor= (int*)(ws + CUR_OFF);
    float4* bb_lo = (float4*)(ws + BBLO_OFF);
    float4* bb_hi = (float4*)(ws + BBHI_OFF);
    unsigned* done= (unsigned*)(ws + DONE_OFF);
    float*  out   = (float*)d_out;

    prepA_kernel<<<2, 1024, 0, stream>>>(coords, cellid, cursor, done);
    scatter_kernel<<<64, 256, 0, stream>>>(coords, scores, cellid, cursor, pk_s, s_s);
    bbox_kernel<<<4, 256, 0, stream>>>(pk_s, bb_lo, bb_hi);
    knnrank_kernel<<<512, 1024, 0, stream>>>(pk_s, s_s, bb_lo, bb_hi, knn, rank);
    lossfin_kernel<<<LOSS_BLOCKS, 256, 0, stream>>>(s_s, pk_s, knn, rank, part, done, out);
}